// Round 1
// baseline (968.380 us; speedup 1.0000x reference)
//
#include <hip/hip_runtime.h>
#include <hip/hip_bf16.h>
#include <math.h>

// Problem constants (fixed by setup_inputs)
// B=2, L=1024, D=1024, H=16, HD=64
// attn_score = (1 + dist/64)^(-65.5); probs_ij = s_ij*nc_j^-0.5 / sum_j(s_ij*nc_j^-0.5)
// (the N_R^{-0.5} factor cancels in the row normalization)

#define B_SZ 2
#define L_SZ 1024
#define D_SZ 1024
#define NH 16
#define HD_SZ 64
#define BH (B_SZ * NH)          // 32
#define HEAD_ELEMS (L_SZ * HD_SZ)  // 65536 per (b,h)

// ---------------------------------------------------------------------------
// Generic 64x64-tile f32 GEMM: Y = X[M=2048][1024] @ W[1024][1024] + bias
// headMode=1: scatter output to [B][H][L][64] layout; headMode=0: row-major.
// ---------------------------------------------------------------------------
__global__ __launch_bounds__(256) void gemm64(const float* __restrict__ X,
                                              const float* __restrict__ W,
                                              const float* __restrict__ bias,
                                              float* __restrict__ Y,
                                              int headMode) {
  __shared__ float As[16][68];
  __shared__ float Bs[16][68];
  const int bm = blockIdx.x * 64;
  const int bn = blockIdx.y * 64;
  const int tid = threadIdx.x;
  const int tx = tid & 15, ty = tid >> 4;
  float acc[4][4] = {};

  for (int k0 = 0; k0 < 1024; k0 += 16) {
#pragma unroll
    for (int it = 0; it < 4; ++it) {
      int idx = tid + it * 256;
      int m = idx >> 4, kk = idx & 15;
      As[kk][m] = X[(size_t)(bm + m) * 1024 + k0 + kk];
    }
#pragma unroll
    for (int it = 0; it < 4; ++it) {
      int idx = tid + it * 256;
      int kk = idx >> 6, n = idx & 63;
      Bs[kk][n] = W[(size_t)(k0 + kk) * 1024 + bn + n];
    }
    __syncthreads();
#pragma unroll
    for (int kk = 0; kk < 16; ++kk) {
      float a[4], b[4];
#pragma unroll
      for (int i = 0; i < 4; ++i) a[i] = As[kk][ty * 4 + i];
#pragma unroll
      for (int j = 0; j < 4; ++j) b[j] = Bs[kk][tx * 4 + j];
#pragma unroll
      for (int i = 0; i < 4; ++i)
#pragma unroll
        for (int j = 0; j < 4; ++j) acc[i][j] += a[i] * b[j];
    }
    __syncthreads();
  }

#pragma unroll
  for (int i = 0; i < 4; ++i) {
    int m = bm + ty * 4 + i;
#pragma unroll
    for (int j = 0; j < 4; ++j) {
      int n = bn + tx * 4 + j;
      float v = acc[i][j] + bias[n];
      if (headMode) {
        int bb = m >> 10, l = m & 1023;
        int h = n >> 6, hd = n & 63;
        Y[(((size_t)(bb * NH + h) * L_SZ) + l) * HD_SZ + hd] = v;
      } else {
        Y[(size_t)m * 1024 + n] = v;
      }
    }
  }
}

// ---------------------------------------------------------------------------
// Pass A: column sums of the score matrix per (b,h); store N_C^{-0.5}.
// grid = (BH, L/64); block owns 64 columns, iterates all 1024 rows.
// ---------------------------------------------------------------------------
__global__ __launch_bounds__(256) void colsum_k(const float* __restrict__ Q,
                                                const float* __restrict__ Kt,
                                                float* __restrict__ RNC) {
  const int bh = blockIdx.x;
  const int jt = blockIdx.y * 64;
  const int tid = threadIdx.x;
  __shared__ float Ks[64][65];
  __shared__ float k2s[64];
  __shared__ float q2all[1024];
  __shared__ float Qs16[16][65];
  __shared__ float red[4][64];

  const float* Qb = Q + (size_t)bh * HEAD_ELEMS;
  const float* Kb = Kt + (size_t)bh * HEAD_ELEMS;

  // stage the 64 K rows this block owns
#pragma unroll
  for (int itr = 0; itr < 16; ++itr) {
    int idx = tid + itr * 256;
    int j = idx >> 6, d = idx & 63;
    Ks[j][d] = Kb[(size_t)(jt + j) * 64 + d];
  }
  // q^2 table for all rows
#pragma unroll
  for (int itr = 0; itr < 4; ++itr) {
    int i = tid + itr * 256;
    const float* qr = Qb + (size_t)i * 64;
    float s = 0.f;
#pragma unroll
    for (int d = 0; d < 64; ++d) { float x = qr[d]; s += x * x; }
    q2all[i] = s;
  }
  __syncthreads();
  if (tid < 64) {
    float s = 0.f;
#pragma unroll
    for (int d = 0; d < 64; ++d) { float x = Ks[tid][d]; s += x * x; }
    k2s[tid] = s;
  }
  __syncthreads();

  const int j = tid & 63, r = tid >> 6;
  float colacc = 0.f;

  for (int i0 = 0; i0 < 1024; i0 += 16) {
#pragma unroll
    for (int itr = 0; itr < 4; ++itr) {
      int idx = tid + itr * 256;
      int ii = idx >> 6, d = idx & 63;
      Qs16[ii][d] = Qb[(size_t)(i0 + ii) * 64 + d];
    }
    __syncthreads();
#pragma unroll
    for (int s4 = 0; s4 < 4; ++s4) {
      int ii = r * 4 + s4;
      float dot = 0.f;
#pragma unroll
      for (int d = 0; d < 64; ++d) dot += Qs16[ii][d] * Ks[j][d];
      float d2 = fmaxf(q2all[i0 + ii] + k2s[j] - 2.f * dot, 1e-12f);
      float g = sqrtf(d2) * 0.015625f;  // /64
      colacc += expf(-65.5f * log1pf(g));
    }
    __syncthreads();
  }

  red[r][j] = colacc;
  __syncthreads();
  if (tid < 64) {
    float s = red[0][tid] + red[1][tid] + red[2][tid] + red[3][tid];
    RNC[(size_t)bh * 1024 + jt + tid] = 1.0f / sqrtf(s);
  }
}

// ---------------------------------------------------------------------------
// Pass B: recompute scores, weight by N_C^{-0.5}, row-normalize, multiply V.
// grid = (BH, L/64); block owns 64 query rows. Writes AO in [B][L][1024].
// ---------------------------------------------------------------------------
__global__ __launch_bounds__(256) void attn_out_k(const float* __restrict__ Q,
                                                  const float* __restrict__ Kt,
                                                  const float* __restrict__ V,
                                                  const float* __restrict__ RNC,
                                                  float* __restrict__ AO) {
  const int bh = blockIdx.x;
  const int it0 = blockIdx.y * 64;
  const int tid = threadIdx.x;
  const int bb = bh >> 4, h = bh & 15;
  __shared__ float Qs[64][65];
  __shared__ float q2s[64];
  __shared__ float k2all[1024];
  __shared__ float rncs[1024];
  __shared__ float Ks16[16][65];
  __shared__ float Vs16[16][64];
  __shared__ float Ws[16][65];
  __shared__ float red[4][64];

  const float* Qb = Q + (size_t)bh * HEAD_ELEMS;
  const float* Kb = Kt + (size_t)bh * HEAD_ELEMS;
  const float* Vb = V + (size_t)bh * HEAD_ELEMS;

#pragma unroll
  for (int itr = 0; itr < 16; ++itr) {
    int idx = tid + itr * 256;
    int i = idx >> 6, d = idx & 63;
    Qs[i][d] = Qb[(size_t)(it0 + i) * 64 + d];
  }
#pragma unroll
  for (int itr = 0; itr < 4; ++itr) {
    int jj = tid + itr * 256;
    const float* kr = Kb + (size_t)jj * 64;
    float s = 0.f;
#pragma unroll
    for (int d = 0; d < 64; ++d) { float x = kr[d]; s += x * x; }
    k2all[jj] = s;
    rncs[jj] = RNC[(size_t)bh * 1024 + jj];
  }
  __syncthreads();
  if (tid < 64) {
    float s = 0.f;
#pragma unroll
    for (int d = 0; d < 64; ++d) { float x = Qs[tid][d]; s += x * x; }
    q2s[tid] = s;
  }
  __syncthreads();

  const int i = tid & 63, r = tid >> 6;        // phase-1 ids
  const int i2 = tid >> 2, db = (tid & 3) * 16;  // phase-2 ids
  float dacc = 0.f;
  float oacc[16];
#pragma unroll
  for (int dd = 0; dd < 16; ++dd) oacc[dd] = 0.f;

  for (int j0 = 0; j0 < 1024; j0 += 16) {
#pragma unroll
    for (int itr = 0; itr < 4; ++itr) {
      int idx = tid + itr * 256;
      int jj = idx >> 6, d = idx & 63;
      Ks16[jj][d] = Kb[(size_t)(j0 + jj) * 64 + d];
      Vs16[jj][d] = Vb[(size_t)(j0 + jj) * 64 + d];
    }
    __syncthreads();
#pragma unroll
    for (int s4 = 0; s4 < 4; ++s4) {
      int jj = r * 4 + s4;
      float dot = 0.f;
#pragma unroll
      for (int d = 0; d < 64; ++d) dot += Qs[i][d] * Ks16[jj][d];
      float d2 = fmaxf(q2s[i] + k2all[j0 + jj] - 2.f * dot, 1e-12f);
      float g = sqrtf(d2) * 0.015625f;
      float w = expf(-65.5f * log1pf(g)) * rncs[j0 + jj];
      Ws[jj][i] = w;
      dacc += w;
    }
    __syncthreads();
#pragma unroll
    for (int jj = 0; jj < 16; ++jj) {
      float wv = Ws[jj][i2];
#pragma unroll
      for (int dd = 0; dd < 16; ++dd) oacc[dd] += wv * Vs16[jj][db + dd];
    }
    __syncthreads();
  }

  red[r][i] = dacc;
  __syncthreads();
  float denom = red[0][i2] + red[1][i2] + red[2][i2] + red[3][i2];
  float inv = 1.0f / denom;
  float* aorow = AO + ((size_t)(bb * L_SZ + it0 + i2)) * D_SZ + h * 64 + db;
#pragma unroll
  for (int dd = 0; dd < 16; ++dd) aorow[dd] = oacc[dd] * inv;
}

// ---------------------------------------------------------------------------
extern "C" void kernel_launch(void* const* d_in, const int* in_sizes, int n_in,
                              void* d_out, int out_size, void* d_ws, size_t ws_size,
                              hipStream_t stream) {
  const float* x  = (const float*)d_in[0];
  const float* WQ = (const float*)d_in[1];
  const float* bQ = (const float*)d_in[2];
  const float* WK = (const float*)d_in[3];
  const float* bK = (const float*)d_in[4];
  const float* WV = (const float*)d_in[5];
  const float* bV = (const float*)d_in[6];
  const float* WO = (const float*)d_in[7];
  const float* bO = (const float*)d_in[8];
  float* out = (float*)d_out;

  float* w = (float*)d_ws;
  const size_t headTot = (size_t)BH * HEAD_ELEMS;  // 2,097,152 floats
  float* Q   = w;
  float* K   = w + headTot;
  float* V   = w + 2 * headTot;
  float* RNC = w + 3 * headTot;                    // 32768 floats
  float* AO  = RNC + (size_t)BH * 1024;            // 2,097,152 floats

  dim3 ggrid(32, 16);  // M/64=32, N/64=16
  gemm64<<<ggrid, 256, 0, stream>>>(x, WQ, bQ, Q, 1);
  gemm64<<<ggrid, 256, 0, stream>>>(x, WK, bK, K, 1);
  gemm64<<<ggrid, 256, 0, stream>>>(x, WV, bV, V, 1);

  dim3 agrid(BH, 16);  // 32 x (1024/64)
  colsum_k<<<agrid, 256, 0, stream>>>(Q, K, RNC);
  attn_out_k<<<agrid, 256, 0, stream>>>(Q, K, V, RNC, AO);

  gemm64<<<ggrid, 256, 0, stream>>>(AO, WO, bO, out, 0);
}

// Round 2
// 275.072 us; speedup vs baseline: 3.5205x; 3.5205x over previous
//
#include <hip/hip_runtime.h>
#include <math.h>

// B=2, L=1024, D=1024, H=16, HD=64.
// probs_ij = s_ij*nc_j^-0.5 / sum_j(s_ij*nc_j^-0.5)   (N_R^-0.5 cancels)
// s_ij = (1 + dist_ij/64)^(-65.5), dist from bf16-rounded Q,K (consistent q2/k2).

typedef __attribute__((ext_vector_type(8))) short short8;
typedef __attribute__((ext_vector_type(4))) float f32x4;

__device__ inline unsigned short f2bf(float f) {
  unsigned int u = __float_as_uint(f);
  unsigned int r = (u + 0x7FFFu + ((u >> 16) & 1u)) >> 16;
  return (unsigned short)r;
}

__device__ inline float bf2f(unsigned short s) {
  return __uint_as_float(((unsigned int)s) << 16);
}

__device__ inline float score_fn(float dot, float sq) {
  float d2 = fmaxf(fmaf(-2.f, dot, sq), 1e-12f);
  float g = __builtin_amdgcn_sqrtf(d2) * 0.015625f;   // dist/64
  return __builtin_amdgcn_exp2f(-65.5f * __builtin_amdgcn_logf(1.f + g));
}

// ---------------------------------------------------------------------------
// x f32 -> bf16 (straight copy-convert), 4 elems/thread
__global__ __launch_bounds__(256) void cvt_f32_bf16(const float* __restrict__ in,
                                                    unsigned short* __restrict__ out) {
  int i = blockIdx.x * 256 + threadIdx.x;
  float4 v = ((const float4*)in)[i];
  out[4 * i + 0] = f2bf(v.x);
  out[4 * i + 1] = f2bf(v.y);
  out[4 * i + 2] = f2bf(v.z);
  out[4 * i + 3] = f2bf(v.w);
}

// W f32 [k][n] -> WT bf16 [n][k]
__global__ __launch_bounds__(256) void wtrans(const float* __restrict__ W,
                                              unsigned short* __restrict__ WT) {
  __shared__ float T[32][33];
  int k0 = blockIdx.x * 32, n0 = blockIdx.y * 32;
  int c = threadIdx.x & 31, r8 = threadIdx.x >> 5;
#pragma unroll
  for (int it = 0; it < 4; ++it) {
    int rr = r8 + it * 8;
    T[rr][c] = W[(size_t)(k0 + rr) * 1024 + n0 + c];
  }
  __syncthreads();
#pragma unroll
  for (int it = 0; it < 4; ++it) {
    int rr = r8 + it * 8;
    WT[(size_t)(n0 + rr) * 1024 + k0 + c] = f2bf(T[c][rr]);
  }
}

// ---------------------------------------------------------------------------
// MFMA GEMM: A bf16 [2048][1024] @ W (given as WT bf16 [n][k]) + bias.
// mode 0: bf16 out, head layout [bh][l][64]
// mode 1: bf16 out, V^T layout  [bh][64][1024]
// mode 2: f32 out, row-major [2048][1024]
__global__ __launch_bounds__(256) void gemm_mfma(const unsigned short* __restrict__ A,
                                                 const unsigned short* __restrict__ BT,
                                                 const float* __restrict__ bias,
                                                 void* __restrict__ Y, int mode) {
  int tid = threadIdx.x;
  int w = tid >> 6, l = tid & 63;
  int g = l >> 4, l15 = l & 15;
  int i0 = blockIdx.x * 64 + w * 16;
  int n0 = blockIdx.y * 64;

  f32x4 acc[4];
#pragma unroll
  for (int t = 0; t < 4; ++t)
#pragma unroll
    for (int r = 0; r < 4; ++r) acc[t][r] = 0.f;

  for (int k0 = 0; k0 < 1024; k0 += 32) {
    short8 a = *(const short8*)&A[(size_t)(i0 + l15) * 1024 + k0 + 8 * g];
#pragma unroll
    for (int t = 0; t < 4; ++t) {
      short8 b = *(const short8*)&BT[(size_t)(n0 + 16 * t + l15) * 1024 + k0 + 8 * g];
      acc[t] = __builtin_amdgcn_mfma_f32_16x16x32_bf16(a, b, acc[t], 0, 0, 0);
    }
  }

#pragma unroll
  for (int t = 0; t < 4; ++t) {
    int n = n0 + 16 * t + l15;
    float bv = bias[n];
#pragma unroll
    for (int r = 0; r < 4; ++r) {
      int m = i0 + 4 * g + r;
      float v = acc[t][r] + bv;
      if (mode == 0) {
        int b = m >> 10, ll = m & 1023, h = n >> 6, hd = n & 63;
        ((unsigned short*)Y)[(((size_t)(b * 16 + h) * 1024) + ll) * 64 + hd] = f2bf(v);
      } else if (mode == 1) {
        int b = m >> 10, ll = m & 1023, h = n >> 6, hd = n & 63;
        ((unsigned short*)Y)[(((size_t)(b * 16 + h) * 64) + hd) * 1024 + ll] = f2bf(v);
      } else {
        ((float*)Y)[(size_t)m * 1024 + n] = v;
      }
    }
  }
}

// ---------------------------------------------------------------------------
// Row sums-of-squares of Q,K (bf16 head layout) -> q2,k2 f32
__global__ __launch_bounds__(256) void sqnorm(const unsigned short* __restrict__ Qb,
                                              const unsigned short* __restrict__ Kb,
                                              float* __restrict__ q2,
                                              float* __restrict__ k2) {
  int row = blockIdx.x * 256 + threadIdx.x;
  const unsigned short* src = blockIdx.y ? Kb : Qb;
  float* dst = blockIdx.y ? k2 : q2;
  const short8* p = (const short8*)&src[(size_t)row * 64];
  float s = 0.f;
#pragma unroll
  for (int c = 0; c < 8; ++c) {
    short8 v = p[c];
#pragma unroll
    for (int e = 0; e < 8; ++e) {
      float f = bf2f((unsigned short)v[e]);
      s = fmaf(f, f, s);
    }
  }
  dst[row] = s;
}

// ---------------------------------------------------------------------------
// Pass A: column sums of score matrix -> rnc = colsum^-0.5.
// grid (32 bh, 16 jtiles); wave w owns 16 cols, loops all 1024 rows.
__global__ __launch_bounds__(256) void colsum_mfma(const unsigned short* __restrict__ Qb,
                                                   const unsigned short* __restrict__ Kb,
                                                   const float* __restrict__ q2,
                                                   const float* __restrict__ k2,
                                                   float* __restrict__ rnc) {
  int bh = blockIdx.x, jt = blockIdx.y;
  int tid = threadIdx.x, w = tid >> 6, l = tid & 63;
  int g = l >> 4, l15 = l & 15;
  const size_t hb = (size_t)bh * 1024;
  int j = jt * 64 + w * 16 + l15;

  short8 bk0 = *(const short8*)&Kb[(hb + j) * 64 + 8 * g];
  short8 bk1 = *(const short8*)&Kb[(hb + j) * 64 + 32 + 8 * g];
  float k2j = k2[hb + j];
  float colacc = 0.f;

  for (int i0 = 0; i0 < 1024; i0 += 16) {
    short8 a0 = *(const short8*)&Qb[(hb + i0 + l15) * 64 + 8 * g];
    short8 a1 = *(const short8*)&Qb[(hb + i0 + l15) * 64 + 32 + 8 * g];
    f32x4 c;
#pragma unroll
    for (int r = 0; r < 4; ++r) c[r] = 0.f;
    c = __builtin_amdgcn_mfma_f32_16x16x32_bf16(a0, bk0, c, 0, 0, 0);
    c = __builtin_amdgcn_mfma_f32_16x16x32_bf16(a1, bk1, c, 0, 0, 0);
    float4 qv = *(const float4*)&q2[hb + i0 + 4 * g];
    colacc += score_fn(c[0], qv.x + k2j);
    colacc += score_fn(c[1], qv.y + k2j);
    colacc += score_fn(c[2], qv.z + k2j);
    colacc += score_fn(c[3], qv.w + k2j);
  }
  colacc += __shfl_xor(colacc, 16);
  colacc += __shfl_xor(colacc, 32);
  if (l < 16) rnc[hb + jt * 64 + w * 16 + l] = __builtin_amdgcn_rsqf(colacc);
}

// ---------------------------------------------------------------------------
// Pass B: recompute scores, weight by rnc, row-normalize, P@V via MFMA.
// grid (32 bh, 16 itiles); wave w owns 16 rows; P staged in wave-private LDS.
__global__ __launch_bounds__(256) void attn_mfma(const unsigned short* __restrict__ Qb,
                                                 const unsigned short* __restrict__ Kb,
                                                 const unsigned short* __restrict__ VT,
                                                 const float* __restrict__ q2,
                                                 const float* __restrict__ k2,
                                                 const float* __restrict__ rnc,
                                                 unsigned short* __restrict__ AO) {
  __shared__ unsigned short P[4][16 * 40];  // per-wave, rows padded to 80 B
  int bh = blockIdx.x;
  int tid = threadIdx.x, w = tid >> 6, l = tid & 63;
  int g = l >> 4, l15 = l & 15;
  int it0 = blockIdx.y * 64 + w * 16;
  const size_t hb = (size_t)bh * 1024;
  int b = bh >> 4, h = bh & 15;

  short8 aq0 = *(const short8*)&Qb[(hb + it0 + l15) * 64 + 8 * g];
  short8 aq1 = *(const short8*)&Qb[(hb + it0 + l15) * 64 + 32 + 8 * g];
  float4 qvv = *(const float4*)&q2[hb + it0 + 4 * g];
  float qva[4] = {qvv.x, qvv.y, qvv.z, qvv.w};

  f32x4 o[4];
#pragma unroll
  for (int t = 0; t < 4; ++t)
#pragma unroll
    for (int r = 0; r < 4; ++r) o[t][r] = 0.f;
  float dacc[4] = {0.f, 0.f, 0.f, 0.f};
  unsigned short* Pw = &P[w][0];

  for (int j0 = 0; j0 < 1024; j0 += 32) {
#pragma unroll
    for (int jj = 0; jj < 2; ++jj) {
      int jb = j0 + jj * 16;
      short8 bk0 = *(const short8*)&Kb[(hb + jb + l15) * 64 + 8 * g];
      short8 bk1 = *(const short8*)&Kb[(hb + jb + l15) * 64 + 32 + 8 * g];
      f32x4 c;
#pragma unroll
      for (int r = 0; r < 4; ++r) c[r] = 0.f;
      c = __builtin_amdgcn_mfma_f32_16x16x32_bf16(aq0, bk0, c, 0, 0, 0);
      c = __builtin_amdgcn_mfma_f32_16x16x32_bf16(aq1, bk1, c, 0, 0, 0);
      float k2j = k2[hb + jb + l15];
      float rj = rnc[hb + jb + l15];
#pragma unroll
      for (int r = 0; r < 4; ++r) {
        float s = score_fn(c[r], qva[r] + k2j) * rj;
        dacc[r] += s;
        Pw[(4 * g + r) * 40 + jj * 16 + l15] = f2bf(s);
      }
    }
    __threadfence_block();  // make P writes visible (wave-internal, LDS in-order)
    short8 pf = *(const short8*)&Pw[l15 * 40 + 8 * g];
#pragma unroll
    for (int t = 0; t < 4; ++t) {
      short8 bv = *(const short8*)&VT[((size_t)bh * 64 + 16 * t + l15) * 1024 + j0 + 8 * g];
      o[t] = __builtin_amdgcn_mfma_f32_16x16x32_bf16(pf, bv, o[t], 0, 0, 0);
    }
    __threadfence_block();  // WAR: next iter's writes after this read
  }

#pragma unroll
  for (int r = 0; r < 4; ++r) {
    float d = dacc[r];
    d += __shfl_xor(d, 1);
    d += __shfl_xor(d, 2);
    d += __shfl_xor(d, 4);
    d += __shfl_xor(d, 8);
    dacc[r] = 1.f / d;
  }
#pragma unroll
  for (int t = 0; t < 4; ++t) {
#pragma unroll
    for (int r = 0; r < 4; ++r) {
      int m = b * 1024 + it0 + 4 * g + r;
      int n = h * 64 + 16 * t + l15;
      AO[(size_t)m * 1024 + n] = f2bf(o[t][r] * dacc[r]);
    }
  }
}

// ---------------------------------------------------------------------------
extern "C" void kernel_launch(void* const* d_in, const int* in_sizes, int n_in,
                              void* d_out, int out_size, void* d_ws, size_t ws_size,
                              hipStream_t stream) {
  const float* x  = (const float*)d_in[0];
  const float* WQ = (const float*)d_in[1];
  const float* bQ = (const float*)d_in[2];
  const float* WK = (const float*)d_in[3];
  const float* bK = (const float*)d_in[4];
  const float* WV = (const float*)d_in[5];
  const float* bV = (const float*)d_in[6];
  const float* WO = (const float*)d_in[7];
  const float* bO = (const float*)d_in[8];

  char* base = (char*)d_ws;
  unsigned short* xb  = (unsigned short*)(base);
  unsigned short* WQT = (unsigned short*)(base + (4u  << 20));
  unsigned short* WKT = (unsigned short*)(base + (6u  << 20));
  unsigned short* WVT = (unsigned short*)(base + (8u  << 20));
  unsigned short* WOT = (unsigned short*)(base + (10u << 20));
  unsigned short* Qb  = (unsigned short*)(base + (12u << 20));
  unsigned short* Kb  = (unsigned short*)(base + (16u << 20));
  unsigned short* VTb = (unsigned short*)(base + (20u << 20));
  unsigned short* AOb = (unsigned short*)(base + (24u << 20));
  float* q2  = (float*)(base + (28u << 20));
  float* k2  = (float*)(base + (28u << 20) + (128u << 10));
  float* rnc = (float*)(base + (28u << 20) + (256u << 10));

  cvt_f32_bf16<<<2048, 256, 0, stream>>>(x, xb);
  wtrans<<<dim3(32, 32), 256, 0, stream>>>(WQ, WQT);
  wtrans<<<dim3(32, 32), 256, 0, stream>>>(WK, WKT);
  wtrans<<<dim3(32, 32), 256, 0, stream>>>(WV, WVT);
  wtrans<<<dim3(32, 32), 256, 0, stream>>>(WO, WOT);

  gemm_mfma<<<dim3(32, 16), 256, 0, stream>>>(xb, WQT, bQ, Qb, 0);
  gemm_mfma<<<dim3(32, 16), 256, 0, stream>>>(xb, WKT, bK, Kb, 0);
  gemm_mfma<<<dim3(32, 16), 256, 0, stream>>>(xb, WVT, bV, VTb, 1);

  sqnorm<<<dim3(128, 2), 256, 0, stream>>>(Qb, Kb, q2, k2);
  colsum_mfma<<<dim3(32, 16), 256, 0, stream>>>(Qb, Kb, q2, k2, rnc);
  attn_mfma<<<dim3(32, 16), 256, 0, stream>>>(Qb, Kb, VTb, q2, k2, rnc, AOb);

  gemm_mfma<<<dim3(32, 16), 256, 0, stream>>>(AOb, WOT, bO, d_out, 2);
}

// Round 3
// 156.671 us; speedup vs baseline: 6.1810x; 1.7557x over previous
//
#include <hip/hip_runtime.h>
#include <math.h>

// B=2, L=1024, D=1024, H=16, HD=64.
// probs_ij = s_ij*nc_j^-0.5 / sum_j(s_ij*nc_j^-0.5)   (N_R^-0.5 cancels)
// s_ij = (1 + dist_ij/64)^(-65.5), dist from bf16-rounded Q,K.

typedef __attribute__((ext_vector_type(8))) short short8;
typedef __attribute__((ext_vector_type(4))) float f32x4;

__device__ inline unsigned short f2bf(float f) {
  unsigned int u = __float_as_uint(f);
  unsigned int r = (u + 0x7FFFu + ((u >> 16) & 1u)) >> 16;
  return (unsigned short)r;
}
__device__ inline float bf2f(unsigned short s) {
  return __uint_as_float(((unsigned int)s) << 16);
}
__device__ inline float score_fn(float dot, float sq) {
  float d2 = fmaxf(fmaf(-2.f, dot, sq), 1e-12f);
  float g = __builtin_amdgcn_sqrtf(d2) * 0.015625f;   // dist/64
  return __builtin_amdgcn_exp2f(-65.5f * __builtin_amdgcn_logf(1.f + g));
}

// ---------------------------------------------------------------------------
__global__ __launch_bounds__(256) void cvt_f32_bf16(const float* __restrict__ in,
                                                    unsigned short* __restrict__ out) {
  int i = blockIdx.x * 256 + threadIdx.x;
  float4 v = ((const float4*)in)[i];
  out[4 * i + 0] = f2bf(v.x);
  out[4 * i + 1] = f2bf(v.y);
  out[4 * i + 2] = f2bf(v.z);
  out[4 * i + 3] = f2bf(v.w);
}

// 4 weight transposes in one launch: W f32 [k][n] -> WT bf16 [n][k]
__global__ __launch_bounds__(256) void wtrans4(const float* __restrict__ W0,
                                               const float* __restrict__ W1,
                                               const float* __restrict__ W2,
                                               const float* __restrict__ W3,
                                               unsigned short* __restrict__ T0,
                                               unsigned short* __restrict__ T1,
                                               unsigned short* __restrict__ T2,
                                               unsigned short* __restrict__ T3) {
  int z = blockIdx.z;
  const float* W = z == 0 ? W0 : z == 1 ? W1 : z == 2 ? W2 : W3;
  unsigned short* WT = z == 0 ? T0 : z == 1 ? T1 : z == 2 ? T2 : T3;
  __shared__ float T[32][33];
  int k0 = blockIdx.x * 32, n0 = blockIdx.y * 32;
  int c = threadIdx.x & 31, r8 = threadIdx.x >> 5;
#pragma unroll
  for (int it = 0; it < 4; ++it) {
    int rr = r8 + it * 8;
    T[rr][c] = W[(size_t)(k0 + rr) * 1024 + n0 + c];
  }
  __syncthreads();
#pragma unroll
  for (int it = 0; it < 4; ++it) {
    int rr = r8 + it * 8;
    WT[(size_t)(n0 + rr) * 1024 + k0 + c] = f2bf(T[c][rr]);
  }
}

// ---------------------------------------------------------------------------
// LDS-staged MFMA GEMM, BM=BN=BK=64, 4 waves, XOR-swizzled 16B chunks.
// z selects among up to 3 (BT, bias, Y, mode) sets.
// mode 0: bf16 head layout [bh][l][64]; 1: bf16 VT [bh][64][1024]; 2: f32 [m][n]
__global__ __launch_bounds__(256) void gemm_st(const unsigned short* __restrict__ A,
                                               const unsigned short* __restrict__ B0,
                                               const unsigned short* __restrict__ B1,
                                               const unsigned short* __restrict__ B2,
                                               const float* __restrict__ c0,
                                               const float* __restrict__ c1,
                                               const float* __restrict__ c2,
                                               void* __restrict__ Y0,
                                               void* __restrict__ Y1,
                                               void* __restrict__ Y2,
                                               int m0, int m1, int m2) {
  int z = blockIdx.z;
  const unsigned short* BT = z == 0 ? B0 : z == 1 ? B1 : B2;
  const float* bias = z == 0 ? c0 : z == 1 ? c1 : c2;
  void* Y = z == 0 ? Y0 : z == 1 ? Y1 : Y2;
  int mode = z == 0 ? m0 : z == 1 ? m1 : m2;

  __shared__ __align__(16) unsigned short As[64 * 64];
  __shared__ __align__(16) unsigned short Bs[64 * 64];
  int tid = threadIdx.x;
  int w = tid >> 6, l = tid & 63, g = l >> 4, l15 = l & 15;
  int bm = blockIdx.x * 64, bn = blockIdx.y * 64;

  int sr = tid >> 2;          // staging row 0..63
  int sj = (tid & 3) * 2;     // logical chunk pair {sj, sj+1}
  int sw0 = (sj ^ (sr & 7)) * 8;
  int sw1 = ((sj + 1) ^ (sr & 7)) * 8;
  const int arow = w * 16 + l15;

  f32x4 acc[4];
#pragma unroll
  for (int t = 0; t < 4; ++t)
#pragma unroll
    for (int r = 0; r < 4; ++r) acc[t][r] = 0.f;

  for (int k0 = 0; k0 < 1024; k0 += 64) {
    short8 av0 = *(const short8*)&A[(size_t)(bm + sr) * 1024 + k0 + sj * 8];
    short8 av1 = *(const short8*)&A[(size_t)(bm + sr) * 1024 + k0 + sj * 8 + 8];
    short8 bv0 = *(const short8*)&BT[(size_t)(bn + sr) * 1024 + k0 + sj * 8];
    short8 bv1 = *(const short8*)&BT[(size_t)(bn + sr) * 1024 + k0 + sj * 8 + 8];
    __syncthreads();  // previous compute done reading LDS
    *(short8*)&As[sr * 64 + sw0] = av0;
    *(short8*)&As[sr * 64 + sw1] = av1;
    *(short8*)&Bs[sr * 64 + sw0] = bv0;
    *(short8*)&Bs[sr * 64 + sw1] = bv1;
    __syncthreads();
#pragma unroll
    for (int kc = 0; kc < 2; ++kc) {
      short8 a = *(const short8*)&As[arow * 64 + ((kc * 4 + g) ^ (arow & 7)) * 8];
#pragma unroll
      for (int t = 0; t < 4; ++t) {
        int brow = t * 16 + l15;
        short8 b = *(const short8*)&Bs[brow * 64 + ((kc * 4 + g) ^ (brow & 7)) * 8];
        acc[t] = __builtin_amdgcn_mfma_f32_16x16x32_bf16(a, b, acc[t], 0, 0, 0);
      }
    }
  }

#pragma unroll
  for (int t = 0; t < 4; ++t) {
    int n = bn + 16 * t + l15;
    float bv = bias[n];
#pragma unroll
    for (int r = 0; r < 4; ++r) {
      int m = bm + w * 16 + 4 * g + r;
      float v = acc[t][r] + bv;
      if (mode == 0) {
        int b = m >> 10, ll = m & 1023, h = n >> 6, hd = n & 63;
        ((unsigned short*)Y)[(((size_t)(b * 16 + h) * 1024) + ll) * 64 + hd] = f2bf(v);
      } else if (mode == 1) {
        int b = m >> 10, ll = m & 1023, h = n >> 6, hd = n & 63;
        ((unsigned short*)Y)[(((size_t)(b * 16 + h) * 64) + hd) * 1024 + ll] = f2bf(v);
      } else {
        ((float*)Y)[(size_t)m * 1024 + n] = v;
      }
    }
  }
}

// ---------------------------------------------------------------------------
__global__ __launch_bounds__(256) void sqnorm(const unsigned short* __restrict__ Qb,
                                              const unsigned short* __restrict__ Kb,
                                              float* __restrict__ q2,
                                              float* __restrict__ k2) {
  int row = blockIdx.x * 256 + threadIdx.x;
  const unsigned short* src = blockIdx.y ? Kb : Qb;
  float* dst = blockIdx.y ? k2 : q2;
  const short8* p = (const short8*)&src[(size_t)row * 64];
  float s = 0.f;
#pragma unroll
  for (int c = 0; c < 8; ++c) {
    short8 v = p[c];
#pragma unroll
    for (int e = 0; e < 8; ++e) {
      float f = bf2f((unsigned short)v[e]);
      s = fmaf(f, f, s);
    }
  }
  dst[row] = s;
}

// ---------------------------------------------------------------------------
// Pass A: column sums -> rnc = colsum^-0.5.
// grid (32 bh, 64 jt16); block owns 16 cols; wave w sums rows w*256..+255.
__global__ __launch_bounds__(256) void colsum_mfma(const unsigned short* __restrict__ Qb,
                                                   const unsigned short* __restrict__ Kb,
                                                   const float* __restrict__ q2,
                                                   const float* __restrict__ k2,
                                                   float* __restrict__ rnc) {
  __shared__ float red[4][16];
  int bh = blockIdx.x, jt = blockIdx.y;
  int tid = threadIdx.x, w = tid >> 6, l = tid & 63;
  int g = l >> 4, l15 = l & 15;
  const size_t hb = (size_t)bh * 1024;
  int j = jt * 16 + l15;

  short8 bk0 = *(const short8*)&Kb[(hb + j) * 64 + 8 * g];
  short8 bk1 = *(const short8*)&Kb[(hb + j) * 64 + 32 + 8 * g];
  float k2j = k2[hb + j];
  float colacc = 0.f;

  for (int s = 0; s < 16; ++s) {
    int i0 = w * 256 + s * 16;
    short8 a0 = *(const short8*)&Qb[(hb + i0 + l15) * 64 + 8 * g];
    short8 a1 = *(const short8*)&Qb[(hb + i0 + l15) * 64 + 32 + 8 * g];
    f32x4 c;
#pragma unroll
    for (int r = 0; r < 4; ++r) c[r] = 0.f;
    c = __builtin_amdgcn_mfma_f32_16x16x32_bf16(a0, bk0, c, 0, 0, 0);
    c = __builtin_amdgcn_mfma_f32_16x16x32_bf16(a1, bk1, c, 0, 0, 0);
    float4 qv = *(const float4*)&q2[hb + i0 + 4 * g];
    colacc += score_fn(c[0], qv.x + k2j);
    colacc += score_fn(c[1], qv.y + k2j);
    colacc += score_fn(c[2], qv.z + k2j);
    colacc += score_fn(c[3], qv.w + k2j);
  }
  colacc += __shfl_xor(colacc, 16);
  colacc += __shfl_xor(colacc, 32);
  if (l < 16) red[w][l] = colacc;
  __syncthreads();
  if (tid < 16) {
    float s = red[0][tid] + red[1][tid] + red[2][tid] + red[3][tid];
    rnc[hb + jt * 16 + tid] = __builtin_amdgcn_rsqf(s);
  }
}

// ---------------------------------------------------------------------------
// Pass B: scores -> *rnc -> row-normalize -> @V.
// grid (32 bh, 64 it16); block owns 16 rows; wave w covers j in [w*256, w*256+256).
__global__ __launch_bounds__(256) void attn_mfma(const unsigned short* __restrict__ Qb,
                                                 const unsigned short* __restrict__ Kb,
                                                 const unsigned short* __restrict__ VT,
                                                 const float* __restrict__ q2,
                                                 const float* __restrict__ k2,
                                                 const float* __restrict__ rnc,
                                                 unsigned short* __restrict__ AO) {
  __shared__ __align__(16) unsigned short P[4][16 * 40];  // per-wave P, 80B rows
  __shared__ float Ls[4][64][21];                          // merge: 16 o + 4 dacc
  int bh = blockIdx.x;
  int tid = threadIdx.x, w = tid >> 6, l = tid & 63;
  int g = l >> 4, l15 = l & 15;
  int it0 = blockIdx.y * 16;
  const size_t hb = (size_t)bh * 1024;
  int b = bh >> 4, h = bh & 15;

  short8 aq0 = *(const short8*)&Qb[(hb + it0 + l15) * 64 + 8 * g];
  short8 aq1 = *(const short8*)&Qb[(hb + it0 + l15) * 64 + 32 + 8 * g];
  float4 qvv = *(const float4*)&q2[hb + it0 + 4 * g];
  float qva[4] = {qvv.x, qvv.y, qvv.z, qvv.w};

  f32x4 o[4];
#pragma unroll
  for (int t = 0; t < 4; ++t)
#pragma unroll
    for (int r = 0; r < 4; ++r) o[t][r] = 0.f;
  float dacc[4] = {0.f, 0.f, 0.f, 0.f};
  unsigned short* Pw = &P[w][0];

  for (int s = 0; s < 8; ++s) {
    int j0 = w * 256 + s * 32;
#pragma unroll
    for (int jj = 0; jj < 2; ++jj) {
      int jb = j0 + jj * 16;
      short8 bk0 = *(const short8*)&Kb[(hb + jb + l15) * 64 + 8 * g];
      short8 bk1 = *(const short8*)&Kb[(hb + jb + l15) * 64 + 32 + 8 * g];
      f32x4 c;
#pragma unroll
      for (int r = 0; r < 4; ++r) c[r] = 0.f;
      c = __builtin_amdgcn_mfma_f32_16x16x32_bf16(aq0, bk0, c, 0, 0, 0);
      c = __builtin_amdgcn_mfma_f32_16x16x32_bf16(aq1, bk1, c, 0, 0, 0);
      float k2j = k2[hb + jb + l15];
      float rj = rnc[hb + jb + l15];
#pragma unroll
      for (int r = 0; r < 4; ++r) {
        float sc = score_fn(c[r], qva[r] + k2j) * rj;
        dacc[r] += sc;
        Pw[(4 * g + r) * 40 + jj * 16 + l15] = f2bf(sc);
      }
    }
    // order LDS writes before the read below; global prefetches stay in flight
    asm volatile("s_waitcnt lgkmcnt(0)" ::: "memory");
    short8 pf = *(const short8*)&Pw[l15 * 40 + 8 * g];
#pragma unroll
    for (int t = 0; t < 4; ++t) {
      short8 bv = *(const short8*)&VT[((size_t)bh * 64 + 16 * t + l15) * 1024 + j0 + 8 * g];
      o[t] = __builtin_amdgcn_mfma_f32_16x16x32_bf16(pf, bv, o[t], 0, 0, 0);
    }
  }

  // partial row sums within this wave's j-range
#pragma unroll
  for (int r = 0; r < 4; ++r) {
    float d = dacc[r];
    d += __shfl_xor(d, 1);
    d += __shfl_xor(d, 2);
    d += __shfl_xor(d, 4);
    d += __shfl_xor(d, 8);
    dacc[r] = d;
  }
  // cross-wave merge
#pragma unroll
  for (int t = 0; t < 4; ++t)
#pragma unroll
    for (int r = 0; r < 4; ++r) Ls[w][l][t * 4 + r] = o[t][r];
#pragma unroll
  for (int r = 0; r < 4; ++r) Ls[w][l][16 + r] = dacc[r];
  __syncthreads();

  // each wave finalizes its own 16-col slice (t == w)
  float ov[4], dv[4];
#pragma unroll
  for (int r = 0; r < 4; ++r) { ov[r] = o[w][r]; dv[r] = dacc[r]; }
#pragma unroll
  for (int ww = 0; ww < 4; ++ww) {
    if (ww == w) continue;
#pragma unroll
    for (int r = 0; r < 4; ++r) {
      ov[r] += Ls[ww][l][w * 4 + r];
      dv[r] += Ls[ww][l][16 + r];
    }
  }
#pragma unroll
  for (int r = 0; r < 4; ++r) {
    int m = b * 1024 + it0 + 4 * g + r;
    int n = h * 64 + w * 16 + l15;
    AO[(size_t)m * 1024 + n] = f2bf(ov[r] / dv[r]);
  }
}

// ---------------------------------------------------------------------------
extern "C" void kernel_launch(void* const* d_in, const int* in_sizes, int n_in,
                              void* d_out, int out_size, void* d_ws, size_t ws_size,
                              hipStream_t stream) {
  const float* x  = (const float*)d_in[0];
  const float* WQ = (const float*)d_in[1];
  const float* bQ = (const float*)d_in[2];
  const float* WK = (const float*)d_in[3];
  const float* bK = (const float*)d_in[4];
  const float* WV = (const float*)d_in[5];
  const float* bV = (const float*)d_in[6];
  const float* WO = (const float*)d_in[7];
  const float* bO = (const float*)d_in[8];

  char* base = (char*)d_ws;
  unsigned short* xb  = (unsigned short*)(base);
  unsigned short* WQT = (unsigned short*)(base + (4u  << 20));
  unsigned short* WKT = (unsigned short*)(base + (6u  << 20));
  unsigned short* WVT = (unsigned short*)(base + (8u  << 20));
  unsigned short* WOT = (unsigned short*)(base + (10u << 20));
  unsigned short* Qb  = (unsigned short*)(base + (12u << 20));
  unsigned short* Kb  = (unsigned short*)(base + (16u << 20));
  unsigned short* VTb = (unsigned short*)(base + (20u << 20));
  unsigned short* AOb = (unsigned short*)(base + (24u << 20));
  float* q2  = (float*)(base + (28u << 20));
  float* k2  = (float*)(base + (28u << 20) + (128u << 10));
  float* rnc = (float*)(base + (28u << 20) + (256u << 10));

  cvt_f32_bf16<<<2048, 256, 0, stream>>>(x, xb);
  wtrans4<<<dim3(32, 32, 4), 256, 0, stream>>>(WQ, WK, WV, WO, WQT, WKT, WVT, WOT);

  // fused Q,K,V projections (z = 0,1,2)
  gemm_st<<<dim3(32, 16, 3), 256, 0, stream>>>(xb, WQT, WKT, WVT, bQ, bK, bV,
                                               Qb, Kb, VTb, 0, 0, 1);

  sqnorm<<<dim3(128, 2), 256, 0, stream>>>(Qb, Kb, q2, k2);
  colsum_mfma<<<dim3(32, 64), 256, 0, stream>>>(Qb, Kb, q2, k2, rnc);
  attn_mfma<<<dim3(32, 64), 256, 0, stream>>>(Qb, Kb, VTb, q2, k2, rnc, AOb);

  // output projection
  gemm_st<<<dim3(32, 16, 1), 256, 0, stream>>>(AOb, WOT, WOT, WOT, bO, bO, bO,
                                               d_out, d_out, d_out, 2, 2, 2);
}